// Round 8
// baseline (251.588 us; speedup 1.0000x reference)
//
#include <hip/hip_runtime.h>
#include <math.h>

// Problem constants (B, N, D2, S = 64, 4096, 128, 512)
#define BB 64
#define NN 4096
#define DD 128
#define SS 512

// ---------------------------------------------------------------------------
// Fused kernel v10, templated on CHUNKS (blocks per b).
//   Evidence model: stream BW ~ (resident waves/CU) x (per-wave outstanding
//   loads). R1: 16 waves x 8-deep (64 VGPR) -> 2.4 TB/s. R7: 32 waves x
//   2-deep (32 VGPR, the (512,8) cap) -> 1.1 TB/s. R4: 8 waves x 8-deep ->
//   1.13 TB/s. Untested quadrant: 32 waves x 8-deep = 256-thr blocks at
//   launch_bounds(256,8) (VGPR cap 64 == R1's natural count) with 2048
//   blocks (CHUNKS=32, 8 blocks/CU). That needs a 4.2 MB workspace, so the
//   launcher checks ws_size and falls back to the proven CHUNKS=16 R1
//   replica if it doesn't fit. Body = R1's verified v2 structure (4 thr/row,
//   8-deep k-loop, barrier-free stream), with the q-phase reading yq
//   directly from global (one barrier total before the stream; ran in R7).
// ---------------------------------------------------------------------------
template <int CH, int WPEU>
__global__ __launch_bounds__(256, WPEU) void fused_kernel(
    const float* __restrict__ y_past, const float* __restrict__ yq,
    const float* __restrict__ w, const int* __restrict__ s_past,
    float* __restrict__ bins_g, float* __restrict__ pmax) {
    constexpr int RPC  = NN / CH;   // rows per chunk
    constexpr int SUBT = RPC / 64;  // 64-row subtiles per chunk
    const int b = blockIdx.x, chunk = blockIdx.y;
    const int t = threadIdx.x;      // 0..255
    const int j = t & 3;            // quarter of row (32 floats)
    const int r = t >> 2;           // row within 64-row subtile

    __shared__ float qsh[DD];
    __shared__ float bins[SS];
    __shared__ float wred[4];

    const float4* gp =
        (const float4*)y_past + ((size_t)b * NN + (size_t)chunk * RPC) * 32;

    // ---- subtile-0 half prefetch + s_past indices (independent of q) ----
    float4 y0[4];
#pragma unroll
    for (int k = 0; k < 4; ++k) y0[k] = gp[(size_t)r * 32 + j * 8 + k];

    int sreg[SUBT];
    if (j == 0) {
#pragma unroll
        for (int s = 0; s < SUBT; ++s)
            sreg[s] = s_past[(size_t)b * NN + chunk * RPC + s * 64 + r];
    }

    bins[t] = 0.f;
    bins[t + 256] = 0.f;

    // ---- q = yq @ w (threads 0..127; yq read directly from global so no
    //      staging barrier; w is L2-resident) ----
    if (t < DD) {
        const float* yqb = yq + b * DD;
        float acc = 0.f;
#pragma unroll
        for (int d = 0; d < DD; ++d) acc = fmaf(yqb[d], w[d * DD + t], acc);
        qsh[t] = acc;
    }

    // ---- the ONE pre-stream barrier ----
    __syncthreads();

    // ---- q fragment (broadcast within j-groups, conflict-free) ----
    float4 qreg[8];
#pragma unroll
    for (int k = 0; k < 8; ++k) qreg[k] = ((const float4*)qsh)[j * 8 + k];

    float pv[SUBT];

    // ---- subtile 0: first half from prefetch regs, second half fresh ----
    {
        float4 acc = {0.f, 0.f, 0.f, 0.f};
#pragma unroll
        for (int k = 0; k < 4; ++k) {
            acc.x = fmaf(qreg[k].x, y0[k].x, acc.x);
            acc.y = fmaf(qreg[k].y, y0[k].y, acc.y);
            acc.z = fmaf(qreg[k].z, y0[k].z, acc.z);
            acc.w = fmaf(qreg[k].w, y0[k].w, acc.w);
        }
#pragma unroll
        for (int k = 4; k < 8; ++k) {
            float4 yv = gp[(size_t)r * 32 + j * 8 + k];
            acc.x = fmaf(qreg[k].x, yv.x, acc.x);
            acc.y = fmaf(qreg[k].y, yv.y, acc.y);
            acc.z = fmaf(qreg[k].z, yv.z, acc.z);
            acc.w = fmaf(qreg[k].w, yv.w, acc.w);
        }
        float p = (acc.x + acc.y) + (acc.z + acc.w);
        p += __shfl_xor(p, 1, 64);
        p += __shfl_xor(p, 2, 64);  // all 4 lanes of row-group hold full dot
        pv[0] = p;
    }

    // ---- subtiles 1..SUBT-1: straight global->reg, no barriers ----
#pragma unroll
    for (int s = 1; s < SUBT; ++s) {
        float4 acc = {0.f, 0.f, 0.f, 0.f};
#pragma unroll
        for (int k = 0; k < 8; ++k) {
            float4 yv = gp[(size_t)(s * 64 + r) * 32 + j * 8 + k];
            acc.x = fmaf(qreg[k].x, yv.x, acc.x);
            acc.y = fmaf(qreg[k].y, yv.y, acc.y);
            acc.z = fmaf(qreg[k].z, yv.z, acc.z);
            acc.w = fmaf(qreg[k].w, yv.w, acc.w);
        }
        float p = (acc.x + acc.y) + (acc.z + acc.w);
        p += __shfl_xor(p, 1, 64);
        p += __shfl_xor(p, 2, 64);
        pv[s] = p;
    }

    // ---- chunk max over RPC rows (4 waves) ----
    float m = pv[0];
#pragma unroll
    for (int s = 1; s < SUBT; ++s) m = fmaxf(m, pv[s]);
#pragma unroll
    for (int off = 32; off > 0; off >>= 1) m = fmaxf(m, __shfl_xor(m, off, 64));
    const int wave = t >> 6, lane = t & 63;
    if (lane == 0) wred[wave] = m;
    __syncthreads();
    m = fmaxf(fmaxf(wred[0], wred[1]), fmaxf(wred[2], wred[3]));

    // ---- scatter exp(p - m_c) into LDS bins (j==0 lane per row group) ----
    if (j == 0) {
#pragma unroll
        for (int s = 0; s < SUBT; ++s)
            atomicAdd(&bins[sreg[s]], __expf(pv[s] - m));
    }
    __syncthreads();

    // ---- write chunk bins + max ----
    float* bg = bins_g + ((size_t)b * CH + chunk) * SS;
    bg[t] = bins[t];
    bg[t + 256] = bins[t + 256];
    if (t == 0) pmax[b * CH + chunk] = m;
}

// ---------------------------------------------------------------------------
// Combine: out[b,s] = (sum_c bins[b,c,s] * exp(m_c - M)) / Z,
// Z recovered as the block-wide sum of the numerators. 64 blocks x 512 thr.
// ---------------------------------------------------------------------------
template <int CH>
__global__ __launch_bounds__(512) void combine_kernel(
    const float* __restrict__ bins_g, const float* __restrict__ pmax,
    float* __restrict__ out) {
    int b = blockIdx.x;
    int t = threadIdx.x;  // 0..511
    __shared__ float scale[CH];
    __shared__ float red[8];
    __shared__ float sInv;

    if (t < CH) scale[t] = pmax[b * CH + t];
    __syncthreads();
    if (t == 0) {
        float M = scale[0];
#pragma unroll
        for (int c = 1; c < CH; ++c) M = fmaxf(M, scale[c]);
#pragma unroll
        for (int c = 0; c < CH; ++c) scale[c] = __expf(scale[c] - M);
    }
    __syncthreads();

    float acc = 0.f;
#pragma unroll
    for (int c = 0; c < CH; ++c)
        acc = fmaf(bins_g[((size_t)b * CH + c) * SS + t], scale[c], acc);

    float s = acc;
#pragma unroll
    for (int off = 32; off > 0; off >>= 1) s += __shfl_xor(s, off, 64);
    if ((t & 63) == 0) red[t >> 6] = s;
    __syncthreads();
    if (t == 0) {
        float S = 0.f;
#pragma unroll
        for (int i = 0; i < 8; ++i) S += red[i];
        sInv = 1.f / S;
    }
    __syncthreads();

    out[b * SS + t] = acc * sInv;
}

// ---------------------------------------------------------------------------
// Launch. Inputs: [0]=s_past(int B*N), [1]=yq(f32 B*D2), [2]=y_past(f32
// B*N*D2), [3]=w_mat(f32 D2*D2), [4]=size_s. Out: post_est f32 B*S.
// ws layout (CH chunks): bins_g (BB*CH*SS f32) | pmax (BB*CH f32).
// CH=32 needs ~4.2 MB; launcher verifies ws_size and falls back to CH=16
// (2.1 MB, the R1-proven config) if the workspace is smaller.
// ---------------------------------------------------------------------------
extern "C" void kernel_launch(void* const* d_in, const int* in_sizes, int n_in,
                              void* d_out, int out_size, void* d_ws, size_t ws_size,
                              hipStream_t stream) {
    const int*   s_past = (const int*)d_in[0];
    const float* yq     = (const float*)d_in[1];
    const float* y_past = (const float*)d_in[2];
    const float* w_mat  = (const float*)d_in[3];

    float* ws  = (float*)d_ws;
    float* out = (float*)d_out;

    const size_t need32 =
        ((size_t)BB * 32 * SS + (size_t)BB * 32) * sizeof(float);

    if (ws_size >= need32) {
        // 32 chunks: 2048 blocks -> 8 blocks/CU x 4 waves = 32 waves/CU at
        // 64 VGPR (launch_bounds(256,8)) -- the waves x depth experiment.
        float* bins_g = ws;                        // BB*32*SS floats
        float* pmax   = bins_g + (size_t)BB * 32 * SS;
        fused_kernel<32, 8><<<dim3(BB, 32), 256, 0, stream>>>(
            y_past, yq, w_mat, s_past, bins_g, pmax);
        combine_kernel<32><<<BB, SS, 0, stream>>>(bins_g, pmax, out);
    } else {
        // Fallback: R1-proven 16-chunk config (16 waves/CU, 2.4 TB/s).
        float* bins_g = ws;                        // BB*16*SS floats
        float* pmax   = bins_g + (size_t)BB * 16 * SS;
        fused_kernel<16, 4><<<dim3(BB, 16), 256, 0, stream>>>(
            y_past, yq, w_mat, s_past, bins_g, pmax);
        combine_kernel<16><<<BB, SS, 0, stream>>>(bins_g, pmax, out);
    }
}

// Round 9
// 208.088 us; speedup vs baseline: 1.2090x; 1.2090x over previous
//
#include <hip/hip_runtime.h>
#include <math.h>

// Problem constants (B, N, D2, S = 64, 4096, 128, 512)
#define BB 64
#define NN 4096
#define DD 128
#define SS 512

// ---------------------------------------------------------------------------
// Fused kernel v11, templated on CHUNKS. The waves x depth experiment,
// corrected: R8 showed __launch_bounds__(256,8) makes the backend collapse
// the load pipeline to ~2-deep (VGPR 32) -- BW fell to 1.13 TB/s despite 32
// waves/CU. This body compiled NATURALLY to 64 VGPR (R2 counter row), and
// 64 VGPR is exactly the 8-waves/EU boundary (512 VGPR/SIMD / 8). So: keep
// the natural compile (no min-waves hint), and supply residency via the
// grid instead: CH=32 -> 2048 blocks -> 8 blocks/CU x 4 waves = 32 waves/CU
// with the full 8-deep load schedule.
//   Model under test (3 consistent points):
//     BW ~ waves x depth:  8wx8d=1.13 TB/s | 16wx8d=2.40 | 32wx2d=1.13
//   Target quadrant: 32w x 8d -> predict ~4.5 TB/s.
// ---------------------------------------------------------------------------
template <int CH>
__global__ __launch_bounds__(256) void fused_kernel(
    const float* __restrict__ y_past, const float* __restrict__ yq,
    const float* __restrict__ w, const int* __restrict__ s_past,
    float* __restrict__ bins_g, float* __restrict__ pmax) {
    constexpr int RPC  = NN / CH;   // rows per chunk
    constexpr int SUBT = RPC / 64;  // 64-row subtiles per chunk
    const int b = blockIdx.x, chunk = blockIdx.y;
    const int t = threadIdx.x;      // 0..255
    const int j = t & 3;            // quarter of row (32 floats)
    const int r = t >> 2;           // row within 64-row subtile

    __shared__ float qsh[DD];
    __shared__ float bins[SS];
    __shared__ float wred[4];

    const float4* gp =
        (const float4*)y_past + ((size_t)b * NN + (size_t)chunk * RPC) * 32;

    // ---- subtile-0 half prefetch + s_past indices (independent of q) ----
    float4 y0[4];
#pragma unroll
    for (int k = 0; k < 4; ++k) y0[k] = gp[(size_t)r * 32 + j * 8 + k];

    int sreg[SUBT];
    if (j == 0) {
#pragma unroll
        for (int s = 0; s < SUBT; ++s)
            sreg[s] = s_past[(size_t)b * NN + chunk * RPC + s * 64 + r];
    }

    bins[t] = 0.f;
    bins[t + 256] = 0.f;

    // ---- q = yq @ w (threads 0..127; yq read directly from global so no
    //      staging barrier; w is L2-resident) ----
    if (t < DD) {
        const float* yqb = yq + b * DD;
        float acc = 0.f;
#pragma unroll
        for (int d = 0; d < DD; ++d) acc = fmaf(yqb[d], w[d * DD + t], acc);
        qsh[t] = acc;
    }

    // ---- the ONE pre-stream barrier ----
    __syncthreads();

    // ---- q fragment (broadcast within j-groups, conflict-free) ----
    float4 qreg[8];
#pragma unroll
    for (int k = 0; k < 8; ++k) qreg[k] = ((const float4*)qsh)[j * 8 + k];

    float pv[SUBT];

    // ---- subtile 0: first half from prefetch regs, second half fresh ----
    {
        float4 acc = {0.f, 0.f, 0.f, 0.f};
#pragma unroll
        for (int k = 0; k < 4; ++k) {
            acc.x = fmaf(qreg[k].x, y0[k].x, acc.x);
            acc.y = fmaf(qreg[k].y, y0[k].y, acc.y);
            acc.z = fmaf(qreg[k].z, y0[k].z, acc.z);
            acc.w = fmaf(qreg[k].w, y0[k].w, acc.w);
        }
#pragma unroll
        for (int k = 4; k < 8; ++k) {
            float4 yv = gp[(size_t)r * 32 + j * 8 + k];
            acc.x = fmaf(qreg[k].x, yv.x, acc.x);
            acc.y = fmaf(qreg[k].y, yv.y, acc.y);
            acc.z = fmaf(qreg[k].z, yv.z, acc.z);
            acc.w = fmaf(qreg[k].w, yv.w, acc.w);
        }
        float p = (acc.x + acc.y) + (acc.z + acc.w);
        p += __shfl_xor(p, 1, 64);
        p += __shfl_xor(p, 2, 64);  // all 4 lanes of row-group hold full dot
        pv[0] = p;
    }

    // ---- subtiles 1..SUBT-1: straight global->reg, no barriers ----
#pragma unroll
    for (int s = 1; s < SUBT; ++s) {
        float4 acc = {0.f, 0.f, 0.f, 0.f};
#pragma unroll
        for (int k = 0; k < 8; ++k) {
            float4 yv = gp[(size_t)(s * 64 + r) * 32 + j * 8 + k];
            acc.x = fmaf(qreg[k].x, yv.x, acc.x);
            acc.y = fmaf(qreg[k].y, yv.y, acc.y);
            acc.z = fmaf(qreg[k].z, yv.z, acc.z);
            acc.w = fmaf(qreg[k].w, yv.w, acc.w);
        }
        float p = (acc.x + acc.y) + (acc.z + acc.w);
        p += __shfl_xor(p, 1, 64);
        p += __shfl_xor(p, 2, 64);
        pv[s] = p;
    }

    // ---- chunk max over RPC rows (4 waves) ----
    float m = pv[0];
#pragma unroll
    for (int s = 1; s < SUBT; ++s) m = fmaxf(m, pv[s]);
#pragma unroll
    for (int off = 32; off > 0; off >>= 1) m = fmaxf(m, __shfl_xor(m, off, 64));
    const int wave = t >> 6, lane = t & 63;
    if (lane == 0) wred[wave] = m;
    __syncthreads();
    m = fmaxf(fmaxf(wred[0], wred[1]), fmaxf(wred[2], wred[3]));

    // ---- scatter exp(p - m_c) into LDS bins (j==0 lane per row group) ----
    if (j == 0) {
#pragma unroll
        for (int s = 0; s < SUBT; ++s)
            atomicAdd(&bins[sreg[s]], __expf(pv[s] - m));
    }
    __syncthreads();

    // ---- write chunk bins + max ----
    float* bg = bins_g + ((size_t)b * CH + chunk) * SS;
    bg[t] = bins[t];
    bg[t + 256] = bins[t + 256];
    if (t == 0) pmax[b * CH + chunk] = m;
}

// ---------------------------------------------------------------------------
// Combine: out[b,s] = (sum_c bins[b,c,s] * exp(m_c - M)) / Z,
// Z recovered as the block-wide sum of the numerators. 64 blocks x 512 thr.
// ---------------------------------------------------------------------------
template <int CH>
__global__ __launch_bounds__(512) void combine_kernel(
    const float* __restrict__ bins_g, const float* __restrict__ pmax,
    float* __restrict__ out) {
    int b = blockIdx.x;
    int t = threadIdx.x;  // 0..511
    __shared__ float scale[CH];
    __shared__ float red[8];
    __shared__ float sInv;

    if (t < CH) scale[t] = pmax[b * CH + t];
    __syncthreads();
    if (t == 0) {
        float M = scale[0];
#pragma unroll
        for (int c = 1; c < CH; ++c) M = fmaxf(M, scale[c]);
#pragma unroll
        for (int c = 0; c < CH; ++c) scale[c] = __expf(scale[c] - M);
    }
    __syncthreads();

    float acc = 0.f;
#pragma unroll
    for (int c = 0; c < CH; ++c)
        acc = fmaf(bins_g[((size_t)b * CH + c) * SS + t], scale[c], acc);

    float s = acc;
#pragma unroll
    for (int off = 32; off > 0; off >>= 1) s += __shfl_xor(s, off, 64);
    if ((t & 63) == 0) red[t >> 6] = s;
    __syncthreads();
    if (t == 0) {
        float S = 0.f;
#pragma unroll
        for (int i = 0; i < 8; ++i) S += red[i];
        sInv = 1.f / S;
    }
    __syncthreads();

    out[b * SS + t] = acc * sInv;
}

// ---------------------------------------------------------------------------
// Launch. Inputs: [0]=s_past(int B*N), [1]=yq(f32 B*D2), [2]=y_past(f32
// B*N*D2), [3]=w_mat(f32 D2*D2), [4]=size_s. Out: post_est f32 B*S.
// ws layout (CH chunks): bins_g (BB*CH*SS f32) | pmax (BB*CH f32).
// CH=32 (~4.2 MB) confirmed to fit in R8; guarded fallback to CH=16 kept.
// ---------------------------------------------------------------------------
extern "C" void kernel_launch(void* const* d_in, const int* in_sizes, int n_in,
                              void* d_out, int out_size, void* d_ws, size_t ws_size,
                              hipStream_t stream) {
    const int*   s_past = (const int*)d_in[0];
    const float* yq     = (const float*)d_in[1];
    const float* y_past = (const float*)d_in[2];
    const float* w_mat  = (const float*)d_in[3];

    float* ws  = (float*)d_ws;
    float* out = (float*)d_out;

    const size_t need32 =
        ((size_t)BB * 32 * SS + (size_t)BB * 32) * sizeof(float);

    if (ws_size >= need32) {
        // 32 chunks: 2048 blocks -> 8 blocks/CU x 4 waves = 32 waves/CU at
        // the NATURAL 64-VGPR compile (8-deep pipeline preserved).
        float* bins_g = ws;                        // BB*32*SS floats
        float* pmax   = bins_g + (size_t)BB * 32 * SS;
        fused_kernel<32><<<dim3(BB, 32), 256, 0, stream>>>(
            y_past, yq, w_mat, s_past, bins_g, pmax);
        combine_kernel<32><<<BB, SS, 0, stream>>>(bins_g, pmax, out);
    } else {
        // Fallback: R1-proven 16-chunk config (16 waves/CU, 2.4 TB/s).
        float* bins_g = ws;                        // BB*16*SS floats
        float* pmax   = bins_g + (size_t)BB * 16 * SS;
        fused_kernel<16><<<dim3(BB, 16), 256, 0, stream>>>(
            y_past, yq, w_mat, s_past, bins_g, pmax);
        combine_kernel<16><<<BB, SS, 0, stream>>>(bins_g, pmax, out);
    }
}

// Round 10
// 205.330 us; speedup vs baseline: 1.2253x; 1.0134x over previous
//
#include <hip/hip_runtime.h>
#include <math.h>

// Problem constants (B, N, D2, S = 64, 4096, 128, 512)
#define BB 64
#define NN 4096
#define DD 128
#define SS 512

// ---------------------------------------------------------------------------
// Fused kernel v12: perfectly-coalesced streaming (copy-ubench address
// pattern). Old layout: 4 lanes/row -> each instruction = 64x16B pieces at
// 128B stride (64 line-requests/instr, 16B used each) -> request-rate bound
// ~2.4 TB/s across R0/R1/R9 regardless of waves/depth. New layout: per
// 16-row (8KB) tile, load k reads a CONTIGUOUS 1KB (lane l -> float4 l),
// identical to the 6.3 TB/s float4-copy pattern. Lane l at load k holds
// row 2k+(l>=32), cols (l&31)*4..+3; per-lane q is ONE float4. Row totals
// via 23-shuffle reduce-scatter (lane ends with total[l&7]; no runtime reg
// indexing), staged to rowtot[] in LDS for the bin scatter.
// Barriers: lgkm-only asm pair (R7-proven), zero vmcnt drains mid-kernel.
// CH=32: 2048 blocks x 256 thr (ws 4.2MB, fits per R8), natural compile.
// ---------------------------------------------------------------------------
template <int CH>
__global__ __launch_bounds__(256) void fused_kernel(
    const float* __restrict__ y_past, const float* __restrict__ yq,
    const float* __restrict__ w, const int* __restrict__ s_past,
    float* __restrict__ bins_g, float* __restrict__ pmax) {
    constexpr int RPC = NN / CH;   // rows per chunk (128 @ CH=32)
    constexpr int RPW = RPC / 4;   // rows per wave (32)
    constexpr int NT  = RPW / 16;  // 16-row tiles per wave (2)
    const int b = blockIdx.x, chunk = blockIdx.y;
    const int t = threadIdx.x;
    const int l = t & 63, wav = t >> 6;

    __shared__ float qsh[DD];
    __shared__ float rowtot[RPC];
    __shared__ float bins[SS];
    __shared__ float wred[4];

    const float4* gp4 =
        (const float4*)y_past + ((size_t)b * NN + (size_t)chunk * RPC) * (DD / 4);
    const int waveBase = wav * RPW * (DD / 4);  // float4 units

    // ---- tile-0 loads: contiguous 1 KB per instruction ----
    float4 yv[8];
#pragma unroll
    for (int k = 0; k < 8; ++k) yv[k] = gp4[waveBase + k * 64 + l];

    int sidx = 0;
    if (t < RPC) sidx = s_past[(size_t)b * NN + chunk * RPC + t];

    bins[t] = 0.f;
    bins[t + 256] = 0.f;

    // ---- q = yq @ w (threads 0..127; yq uniform -> scalar loads) ----
    if (t < DD) {
        const float* yqb = yq + b * DD;
        float acc = 0.f;
#pragma unroll
        for (int d = 0; d < DD; ++d) acc = fmaf(yqb[d], w[d * DD + t], acc);
        qsh[t] = acc;
    }
    asm volatile("s_waitcnt lgkmcnt(0)" ::: "memory");
    __builtin_amdgcn_s_barrier();

    const float4 q4 = ((const float4*)qsh)[l & 31];  // cols (l&31)*4..+3
    const bool g4 = (l & 4) != 0, g2 = (l & 2) != 0, g1 = (l & 1) != 0;
    float mloc = -1e30f;

#pragma unroll
    for (int T = 0; T < NT; ++T) {
        // consume tile T: a[k] = partial dot of row (2k + l>=32), 4 cols
        float a[8];
#pragma unroll
        for (int k = 0; k < 8; ++k) {
            float4 y = yv[k];
            float s = y.x * q4.x;
            s = fmaf(y.y, q4.y, s);
            s = fmaf(y.z, q4.z, s);
            s = fmaf(y.w, q4.w, s);
            a[k] = s;
        }
        // issue tile T+1 loads (fly under the reduce below)
        if (T + 1 < NT) {
#pragma unroll
            for (int k = 0; k < 8; ++k)
                yv[k] = gp4[waveBase + (T + 1) * 512 + k * 64 + l];
        }
        // reduce-scatter across the 32-lane half: lane ends with total[l&7]
#pragma unroll
        for (int k = 0; k < 8; ++k) a[k] += __shfl_xor(a[k], 16, 64);
#pragma unroll
        for (int k = 0; k < 8; ++k) a[k] += __shfl_xor(a[k], 8, 64);
        float b4[4];
#pragma unroll
        for (int k = 0; k < 4; ++k) {
            float send = g4 ? a[k] : a[k + 4];
            float keep = g4 ? a[k + 4] : a[k];
            b4[k] = keep + __shfl_xor(send, 4, 64);
        }
        float b2[2];
#pragma unroll
        for (int k = 0; k < 2; ++k) {
            float send = g2 ? b4[k] : b4[k + 2];
            float keep = g2 ? b4[k + 2] : b4[k];
            b2[k] = keep + __shfl_xor(send, 2, 64);
        }
        {
            float send = g1 ? b2[0] : b2[1];
            float keep = g1 ? b2[1] : b2[0];
            float tot = keep + __shfl_xor(send, 1, 64);
            // lane l holds total of row_in_tile = 2*(l&7) + (l>=32)
            if ((l & 31) < 8)
                rowtot[wav * RPW + T * 16 + 2 * (l & 7) + (l >> 5)] = tot;
            mloc = fmaxf(mloc, tot);
        }
    }

    // ---- chunk max (every lane's tot is some row's total; dups harmless) ----
#pragma unroll
    for (int off = 32; off > 0; off >>= 1)
        mloc = fmaxf(mloc, __shfl_xor(mloc, off, 64));
    if (l == 0) wred[wav] = mloc;
    asm volatile("s_waitcnt lgkmcnt(0)" ::: "memory");
    __builtin_amdgcn_s_barrier();
    const float m = fmaxf(fmaxf(wred[0], wred[1]), fmaxf(wred[2], wred[3]));

    // ---- scatter: thread t owns row t of the chunk ----
    if (t < RPC) atomicAdd(&bins[sidx], __expf(rowtot[t] - m));
    __syncthreads();

    // ---- write chunk bins + max ----
    float* bg = bins_g + ((size_t)b * CH + chunk) * SS;
    bg[t] = bins[t];
    bg[t + 256] = bins[t + 256];
    if (t == 0) pmax[b * CH + chunk] = m;
}

// ---------------------------------------------------------------------------
// Combine: out[b,s] = (sum_c bins[b,c,s] * exp(m_c - M)) / Z,
// Z recovered as the block-wide sum of the numerators. 64 blocks x 512 thr.
// ---------------------------------------------------------------------------
template <int CH>
__global__ __launch_bounds__(512) void combine_kernel(
    const float* __restrict__ bins_g, const float* __restrict__ pmax,
    float* __restrict__ out) {
    int b = blockIdx.x;
    int t = threadIdx.x;  // 0..511
    __shared__ float scale[CH];
    __shared__ float red[8];
    __shared__ float sInv;

    if (t < CH) scale[t] = pmax[b * CH + t];
    __syncthreads();
    if (t == 0) {
        float M = scale[0];
#pragma unroll
        for (int c = 1; c < CH; ++c) M = fmaxf(M, scale[c]);
#pragma unroll
        for (int c = 0; c < CH; ++c) scale[c] = __expf(scale[c] - M);
    }
    __syncthreads();

    float acc = 0.f;
#pragma unroll
    for (int c = 0; c < CH; ++c)
        acc = fmaf(bins_g[((size_t)b * CH + c) * SS + t], scale[c], acc);

    float s = acc;
#pragma unroll
    for (int off = 32; off > 0; off >>= 1) s += __shfl_xor(s, off, 64);
    if ((t & 63) == 0) red[t >> 6] = s;
    __syncthreads();
    if (t == 0) {
        float S = 0.f;
#pragma unroll
        for (int i = 0; i < 8; ++i) S += red[i];
        sInv = 1.f / S;
    }
    __syncthreads();

    out[b * SS + t] = acc * sInv;
}

// ---------------------------------------------------------------------------
// Launch. Inputs: [0]=s_past(int B*N), [1]=yq(f32 B*D2), [2]=y_past(f32
// B*N*D2), [3]=w_mat(f32 D2*D2), [4]=size_s. Out: post_est f32 B*S.
// ws layout (CH chunks): bins_g (BB*CH*SS f32) | pmax (BB*CH f32).
// CH=32 (~4.2 MB) confirmed to fit in R8; guarded fallback to CH=16 kept.
// ---------------------------------------------------------------------------
extern "C" void kernel_launch(void* const* d_in, const int* in_sizes, int n_in,
                              void* d_out, int out_size, void* d_ws, size_t ws_size,
                              hipStream_t stream) {
    const int*   s_past = (const int*)d_in[0];
    const float* yq     = (const float*)d_in[1];
    const float* y_past = (const float*)d_in[2];
    const float* w_mat  = (const float*)d_in[3];

    float* ws  = (float*)d_ws;
    float* out = (float*)d_out;

    const size_t need32 =
        ((size_t)BB * 32 * SS + (size_t)BB * 32) * sizeof(float);

    if (ws_size >= need32) {
        float* bins_g = ws;                        // BB*32*SS floats
        float* pmax   = bins_g + (size_t)BB * 32 * SS;
        fused_kernel<32><<<dim3(BB, 32), 256, 0, stream>>>(
            y_past, yq, w_mat, s_past, bins_g, pmax);
        combine_kernel<32><<<BB, SS, 0, stream>>>(bins_g, pmax, out);
    } else {
        float* bins_g = ws;                        // BB*16*SS floats
        float* pmax   = bins_g + (size_t)BB * 16 * SS;
        fused_kernel<16><<<dim3(BB, 16), 256, 0, stream>>>(
            y_past, yq, w_mat, s_past, bins_g, pmax);
        combine_kernel<16><<<BB, SS, 0, stream>>>(bins_g, pmax, out);
    }
}